// Round 7
// baseline (176.140 us; speedup 1.0000x reference)
//
#include <hip/hip_runtime.h>
#include <cstdint>

#define B_ROWS 32768
#define DIM    256
#define KCODES 1024
#define NSPLIT 4

typedef _Float16 f16x8  __attribute__((ext_vector_type(8)));
typedef float    f32x16 __attribute__((ext_vector_type(16)));

// ws layout:
// [0, 1M):   codebook fp16 hi/lo (NORMALIZED), GRANULE-MAJOR tiles:
//            32 tiles (32 codes each) x 32KB; tile = 2 chunks (depth halves j) x 16KB;
//            chunk = [hi 8K | lo 8K]; plane = [granule g 0..15][code n 0..31][16B].
//            granule (j,g) covers depth elems j*128 + g*8 .. +8.
// [1M,+4K):  ivs[1024] = 1/||c||
// [1M+4K,..) cand float2[NSPLIT][B_ROWS] = {normalized dot, bitcast(k)}

// ---------------- prep: normalize codebook -> granule-major fp16 hi/lo planes ----------------
__global__ __launch_bounds__(64) void vq_prep(const float* __restrict__ cb,
                                              char* __restrict__ cbq,
                                              float* __restrict__ ivs) {
  const int k = blockIdx.x;
  const int L = threadIdx.x;
  float4 c = reinterpret_cast<const float4*>(cb)[k * 64 + L];
  float nrm = c.x * c.x + c.y * c.y + c.z * c.z + c.w * c.w;
#pragma unroll
  for (int off = 32; off; off >>= 1) nrm += __shfl_xor(nrm, off);
  const float invn = 1.0f / sqrtf(nrm);
  if (L == 0) ivs[k] = invn;

  float f[4] = {c.x * invn, c.y * invn, c.z * invn, c.w * invn};
  _Float16 h[4], l[4];
#pragma unroll
  for (int i = 0; i < 4; ++i) {
    h[i] = (_Float16)f[i];
    l[i] = (_Float16)((f[i] - (float)h[i]) * 2048.0f);
  }
  // lane L covers depth elems [L*4, L*4+4): j = L>>5, g = (L>>1)&15, half-granule = L&1
  char* base = cbq + (size_t)(k >> 5) * 32768 + (L >> 5) * 16384 +
               ((L >> 1) & 15) * 512 + (k & 31) * 16 + (L & 1) * 8;
  *reinterpret_cast<uint2*>(base)        = *reinterpret_cast<uint2*>(h);  // hi plane
  *reinterpret_cast<uint2*>(base + 8192) = *reinterpret_cast<uint2*>(l);  // lo plane
}

__device__ __forceinline__ void gld16(const void* g, void* l) {
  __builtin_amdgcn_global_load_lds(
      (const __attribute__((address_space(1))) uint32_t*)g,
      (__attribute__((address_space(3))) uint32_t*)l, 16, 0, 0);
}

// ---------------- main: 32x32x16 MFMA, granule-major LDS (zero hot-loop addr VALU) ----------------
// Block = 128 thr = 2 waves = 64 rows x 256 codes. LDS 32KB dbuf -> 5 blocks/CU.
// Hot loop per k-step: 2 ds_read_b128 (immediate offset) + 3 MFMA.
__global__ __launch_bounds__(128, 2) void vq_main(const float* __restrict__ emb,
                                                  const char* __restrict__ cbq,
                                                  float2* __restrict__ cand) {
  __shared__ uint4 Btile[2][1024];   // 2 x 16KB chunks: [hi 8K | lo 8K]

  const int flat = threadIdx.x;
  const int wave = flat >> 6;
  const int lane = flat & 63;
  const int n    = lane & 31;        // 32x32 MFMA: A-row / B-col index
  const int hh   = lane >> 5;        // k-half within lane

  const int split  = blockIdx.x & (NSPLIT - 1);
  const int rowblk = blockIdx.x >> 2;
  const int code0  = split * 256;    // 8 tiles of 32 codes
  const int row0   = rowblk * 64 + wave * 32;

  // A fragments: 32 rows/wave, full depth, hi+lo = 128 regs. A[m=n][k=c*16+hh*8+j].
  f16x8 Ah[16], Al[16];
  {
    const float* rp = emb + (size_t)(row0 + n) * DIM;
#pragma unroll
    for (int c = 0; c < 16; ++c) {
      const float* p = rp + c * 16 + hh * 8;
      float4 f0 = *reinterpret_cast<const float4*>(p);
      float4 f1 = *reinterpret_cast<const float4*>(p + 4);
      float f[8] = {f0.x, f0.y, f0.z, f0.w, f1.x, f1.y, f1.z, f1.w};
      f16x8 hv, lv;
#pragma unroll
      for (int j = 0; j < 8; ++j) {
        _Float16 t = (_Float16)f[j];
        hv[j] = t;
        lv[j] = (_Float16)((f[j] - (float)t) * 2048.0f);
      }
      Ah[c] = hv;
      Al[c] = lv;
    }
  }

  // stage one 16KB chunk: idx = tile*2 + j; source is linear (granule-major global)
  auto stage = [&](int buf, int idx) {
    const char* src = cbq + (size_t)(split * 8 + (idx >> 1)) * 32768 + (idx & 1) * 16384;
    char* dst = (char*)&Btile[buf][0];
    const int off = flat * 16;       // 128 thr x 16B x 8 = 16KB
#pragma unroll
    for (int r = 0; r < 8; ++r)
      gld16(src + r * 2048 + off, dst + r * 2048 + off);
  };
  stage(0, 0);

  float bd[16];
  int   bk[16];
#pragma unroll
  for (int i = 0; i < 16; ++i) { bd[i] = 0.0f; bk[i] = code0; }

  // per-lane LDS base: granule g = 2c+hh -> addr = (2c+hh)*512 + n*16
  //                  = [hh*512 + n*16] + c*1024  (c as immediate offset)
  const char* vb0 = (const char*)&Btile[0][0] + hh * 512 + n * 16;
  const char* vb1 = (const char*)&Btile[1][0] + hh * 512 + n * 16;

  __syncthreads();                   // chunk 0 staged
  for (int t = 0; t < 8; ++t) {
    f32x16 aA = {}, aB = {}, aC = {};
#pragma unroll
    for (int j = 0; j < 2; ++j) {
      const int idx = t * 2 + j;
      if (idx + 1 < 16) stage((idx + 1) & 1, idx + 1);
      const char* bp = (idx & 1) ? vb1 : vb0;
#pragma unroll
      for (int c = 0; c < 8; ++c) {
        f16x8 bh = *reinterpret_cast<const f16x8*>(bp + c * 1024);
        f16x8 bl = *reinterpret_cast<const f16x8*>(bp + c * 1024 + 8192);
        const int cg = j * 8 + c;
        aA = __builtin_amdgcn_mfma_f32_32x32x16_f16(Ah[cg], bh, aA, 0, 0, 0);
        aB = __builtin_amdgcn_mfma_f32_32x32x16_f16(Al[cg], bh, aB, 0, 0, 0);
        aC = __builtin_amdgcn_mfma_f32_32x32x16_f16(Ah[cg], bl, aC, 0, 0, 0);
      }
      if (idx + 1 < 16) __syncthreads();
    }
    // epilogue: C/D layout col=lane&31, row=(r&3)+8*(r>>2)+4*hh
    const int nc = code0 + t * 32 + n;
#pragma unroll
    for (int r = 0; r < 16; ++r) {
      float d = fmaf(aB[r] + aC[r], 4.8828125e-4f, aA[r]);   // d = hh + (lh+hl)/2048
      if (d * d > bd[r] * bd[r]) { bd[r] = d; bk[r] = nc; }  // strict > keeps smaller k
    }
  }

  // cross-lane argmax over the 32 cols (xor<32 stays within each 32-lane half)
#pragma unroll
  for (int r = 0; r < 16; ++r) {
    float d = bd[r]; int k = bk[r];
#pragma unroll
    for (int m = 1; m < 32; m <<= 1) {
      float d2 = __shfl_xor(d, m);
      int   k2 = __shfl_xor(k, m);
      float g = d * d, g2 = d2 * d2;
      if (g2 > g || (g2 == g && k2 < k)) { d = d2; k = k2; }
    }
    if (n == 0) {
      const int row = row0 + (r & 3) + 8 * (r >> 2) + 4 * hh;
      cand[(size_t)split * B_ROWS + row] = make_float2(d, __int_as_float(k));
    }
  }
}

// ---------------- reduce: pick best split candidate, write z + index ----------------
__global__ __launch_bounds__(256) void vq_reduce(const float2* __restrict__ cand,
                                                 const float* __restrict__ ivs,
                                                 const float* __restrict__ cb,
                                                 float* __restrict__ out) {
  const int wave = threadIdx.x >> 6;
  const int lane = threadIdx.x & 63;
  const int row = blockIdx.x * 4 + wave;

  float best_d = 0.0f;
  int best_k = KCODES;
#pragma unroll
  for (int s = 0; s < NSPLIT; ++s) {
    float2 c = cand[(size_t)s * B_ROWS + row];
    int k = __float_as_int(c.y);
    float g = c.x * c.x, gb = best_d * best_d;
    if (g > gb || (g == gb && k < best_k)) { best_d = c.x; best_k = k; }
  }
  // alpha = dot/||c||^2 = d_norm * (1/||c||)
  const float alpha = best_d * ivs[best_k];
  float4 c4 = reinterpret_cast<const float4*>(cb)[best_k * 64 + lane];
  float4 z = {alpha * c4.x, alpha * c4.y, alpha * c4.z, alpha * c4.w};
  reinterpret_cast<float4*>(out)[(size_t)row * 64 + lane] = z;
  if (lane == 0) out[(size_t)B_ROWS * DIM + row] = (float)best_k;
}

extern "C" void kernel_launch(void* const* d_in, const int* in_sizes, int n_in,
                              void* d_out, int out_size, void* d_ws, size_t ws_size,
                              hipStream_t stream) {
  const float* emb = (const float*)d_in[0];
  const float* cb  = (const float*)d_in[1];
  char*   cbq  = (char*)d_ws;
  float*  ivs  = (float*)((char*)d_ws + (1 << 20));
  float2* cand = (float2*)((char*)d_ws + (1 << 20) + 4096);

  vq_prep<<<KCODES, 64, 0, stream>>>(cb, cbq, ivs);
  vq_main<<<(B_ROWS / 64) * NSPLIT, 128, 0, stream>>>(emb, cbq, cand);
  vq_reduce<<<B_ROWS / 4, 256, 0, stream>>>(cand, ivs, cb, (float*)d_out);
}